// Round 4
// baseline (102.715 us; speedup 1.0000x reference)
//
#include <hip/hip_runtime.h>
#include <math.h>

// NCE loss, sorted-gather pipeline:
//   K1 hist -> K2 scan -> K3 scatter (counting sort of 2B column-gather tasks
//   by column index) -> K4 gather sorted columns into dense[2B][E] ->
//   K5 per-pair dot/logistic from dense -> K6 reduce.
// Sorting makes same-cache-line columns temporally adjacent so L1/L2 dedup
// them (~22-38% of random-gather HBM traffic), plus DRAM row locality.

#define NB 2048

__device__ __forceinline__ float log_sigmoid_f(float x) {
    return fminf(x, 0.0f) - log1pf(expf(-fabsf(x)));
}

__device__ __forceinline__ int task_col(int i, const int* __restrict__ targets,
                                        const int* __restrict__ contexts) {
    const int pair = i >> 1;
    return (i & 1) ? contexts[pair] : targets[pair];
}

// ---- K1: histogram of task columns into NB buckets ----
__global__ __launch_bounds__(256) void hist_kernel(
    const int* __restrict__ targets, const int* __restrict__ contexts,
    int* __restrict__ counts, int T2, int sh)
{
    const int i = blockIdx.x * 256 + threadIdx.x;
    if (i < T2) atomicAdd(&counts[task_col(i, targets, contexts) >> sh], 1);
}

// ---- K2: exclusive scan of counts -> cursors (single block) ----
__global__ __launch_bounds__(1024) void scan_kernel(
    const int* __restrict__ counts, int* __restrict__ cursors, int nb)
{
    __shared__ int a[NB], b[NB];
    for (int i = threadIdx.x; i < NB; i += 1024) a[i] = (i < nb) ? counts[i] : 0;
    __syncthreads();
    int* src = a; int* dst = b;
    for (int off = 1; off < NB; off <<= 1) {
        for (int i = threadIdx.x; i < NB; i += 1024)
            dst[i] = src[i] + (i >= off ? src[i - off] : 0);
        __syncthreads();
        int* t = src; src = dst; dst = t;
    }
    for (int i = threadIdx.x; i < NB; i += 1024)
        if (i < nb) cursors[i] = src[i] - counts[i];   // exclusive
}

// ---- K3: scatter tasks to sorted positions ----
__global__ __launch_bounds__(256) void scatter_kernel(
    const int* __restrict__ targets, const int* __restrict__ contexts,
    int* __restrict__ cursors, int* __restrict__ sorted,
    int* __restrict__ invperm, int T2, int sh)
{
    const int i = blockIdx.x * 256 + threadIdx.x;
    if (i < T2) {
        const int col = task_col(i, targets, contexts);
        const int pos = atomicAdd(&cursors[col >> sh], 1);
        sorted[pos] = i;
        invperm[i]  = pos;
    }
}

// ---- K4: gather sorted columns into dense[pos][E] (E==128) ----
__global__ __launch_bounds__(256) void gather_kernel(
    const float* __restrict__ embed,
    const int* __restrict__ targets, const int* __restrict__ contexts,
    const int* __restrict__ sorted, float* __restrict__ dense,
    int V, int T2)
{
    const int p = threadIdx.x & 15;        // task within block
    const int g = threadIdx.x >> 4;        // e-chunk 0..15 (8 elems each)
    const int pos = blockIdx.x * 16 + p;
    if (pos >= T2) return;
    const int col = task_col(sorted[pos], targets, contexts);
    const int e0 = g * 8;
    const float* src = embed + col;
    float v[8];
    #pragma unroll
    for (int k = 0; k < 8; ++k) v[k] = src[(size_t)(e0 + k) * V];
    float4* dst = (float4*)(dense + (size_t)pos * 128 + e0);
    dst[0] = make_float4(v[0], v[1], v[2], v[3]);
    dst[1] = make_float4(v[4], v[5], v[6], v[7]);
}

// ---- K5: per-pair compute from dense scratch ----
__global__ __launch_bounds__(256) void compute_kernel(
    const float* __restrict__ dense, const int* __restrict__ invperm,
    const float* __restrict__ bias, const float* __restrict__ freq,
    const int* __restrict__ targets, const int* __restrict__ noises,
    float* __restrict__ partials, int B, int NC)
{
    __shared__ float sh_dot[16][17];
    __shared__ float sh_sq [16][17];
    __shared__ float sh_s  [16];
    __shared__ float sh_wred[4];

    const int p = threadIdx.x & 15;
    const int g = threadIdx.x >> 4;
    const int j = blockIdx.x * 16 + p;
    const bool valid = (j < B);

    float contrib = 0.0f;
    float dot = 0.0f, sq = 0.0f;
    float lg0 = 0.0f; bool has0 = false;
    float bval = 0.0f, lgt = 0.0f;

    if (valid) {
        if (g < NC) {
            const int n = noises[j + (size_t)g * B];
            lg0 = logf((float)NC * freq[n]);
            has0 = true;
        }
        if (g == 0) {
            const int t = targets[j];
            bval = bias[t];
            lgt  = logf((float)NC * freq[t]);
        }
        const int e0 = g * 8;
        const float4* qv = (const float4*)(dense + (size_t)invperm[2 * j]     * 128 + e0);
        const float4* rv = (const float4*)(dense + (size_t)invperm[2 * j + 1] * 128 + e0);
        const float4 q0 = qv[0], q1 = qv[1];
        const float4 r0 = rv[0], r1 = rv[1];
        dot = fmaf(q0.x, r0.x, fmaf(q0.y, r0.y, fmaf(q0.z, r0.z, fmaf(q0.w, r0.w,
              fmaf(q1.x, r1.x, fmaf(q1.y, r1.y, fmaf(q1.z, r1.z, q1.w * r1.w)))))));
        sq  = fmaf(q0.x, q0.x, fmaf(q0.y, q0.y, fmaf(q0.z, q0.z, fmaf(q0.w, q0.w,
              fmaf(q1.x, q1.x, fmaf(q1.y, q1.y, fmaf(q1.z, q1.z, fmaf(q1.w, q1.w,
              fmaf(r0.x, r0.x, fmaf(r0.y, r0.y, fmaf(r0.z, r0.z, fmaf(r0.w, r0.w,
              fmaf(r1.x, r1.x, fmaf(r1.y, r1.y, fmaf(r1.z, r1.z, r1.w * r1.w)))))))))))))));
    }
    sh_dot[p][g] = dot;
    sh_sq [p][g] = sq;
    __syncthreads();

    if (threadIdx.x < 16) {
        float d = 0.0f, s2 = 0.0f;
        #pragma unroll
        for (int gg = 0; gg < 16; ++gg) {
            d  += sh_dot[threadIdx.x][gg];
            s2 += sh_sq [threadIdx.x][gg];
        }
        float sval = 0.0f;
        if (valid) {
            sval = (d + bval) / 128.0f;
            const float pos = log_sigmoid_f(sval - lgt);
            contrib += -pos / (float)B + 10.0f * s2 / (128.0f * (float)B);
        }
        sh_s[threadIdx.x] = sval;
    }
    __syncthreads();

    if (valid) {
        const float sval = sh_s[p];
        float nacc = 0.0f;
        if (has0) nacc = log_sigmoid_f(-(sval - lg0));
        for (int k = g + 16; k < NC; k += 16) {
            const int n = noises[j + (size_t)k * B];
            nacc += log_sigmoid_f(-(sval - logf((float)NC * freq[n])));
        }
        contrib += -nacc / (float)B;
    }

    #pragma unroll
    for (int off = 32; off > 0; off >>= 1)
        contrib += __shfl_xor(contrib, off, 64);
    const int wave = threadIdx.x >> 6;
    if ((threadIdx.x & 63) == 0) sh_wred[wave] = contrib;
    __syncthreads();
    if (threadIdx.x == 0)
        partials[blockIdx.x] = sh_wred[0] + sh_wred[1] + sh_wred[2] + sh_wred[3];
}

__global__ __launch_bounds__(256) void reduce_partials_kernel(
    const float* __restrict__ parts, int n, float* __restrict__ out)
{
    __shared__ double sh[256];
    double a = 0.0;
    for (int i = threadIdx.x; i < n; i += 256) a += (double)parts[i];
    sh[threadIdx.x] = a;
    __syncthreads();
    for (int s = 128; s > 0; s >>= 1) {
        if (threadIdx.x < s) sh[threadIdx.x] += sh[threadIdx.x + s];
        __syncthreads();
    }
    if (threadIdx.x == 0) out[0] = (float)sh[0];
}

// ---- fallback (R3 structure) if ws too small ----
__global__ __launch_bounds__(256) void nce_fallback(
    const float* __restrict__ embed, const float* __restrict__ bias,
    const float* __restrict__ freq, const int* __restrict__ targets,
    const int* __restrict__ contexts, const int* __restrict__ noises,
    float* __restrict__ block_partials, int V, int E, int B, int NC)
{
    __shared__ float sh_dot[16][17];
    __shared__ float sh_sq [16][17];
    __shared__ float sh_s  [16];
    __shared__ float sh_wred[4];
    const int p = threadIdx.x & 15;
    const int g = threadIdx.x >> 4;
    const int j = blockIdx.x * 16 + p;
    const bool valid = (j < B);
    float contrib = 0.0f, dot = 0.0f, sq = 0.0f;
    float lg0 = 0.0f; bool has0 = false; float bval = 0.0f, lgt = 0.0f;
    if (valid) {
        const int t = targets[j], c = contexts[j];
        if (g < NC) { const int n = noises[j + (size_t)g * B];
                      lg0 = logf((float)NC * freq[n]); has0 = true; }
        if (g == 0) { bval = bias[t]; lgt = logf((float)NC * freq[t]); }
        const int epc = E / 16, e0 = g * epc;
        const float* ct = embed + t; const float* cc = embed + c;
        #pragma unroll 8
        for (int e = e0; e < e0 + epc; ++e) {
            float qe = ct[(size_t)e * V], re = cc[(size_t)e * V];
            dot = fmaf(qe, re, dot);
            sq  = fmaf(qe, qe, fmaf(re, re, sq));
        }
    }
    sh_dot[p][g] = dot; sh_sq[p][g] = sq;
    __syncthreads();
    if (threadIdx.x < 16) {
        float d = 0.0f, s2 = 0.0f;
        #pragma unroll
        for (int gg = 0; gg < 16; ++gg) { d += sh_dot[threadIdx.x][gg]; s2 += sh_sq[threadIdx.x][gg]; }
        float sval = 0.0f;
        if (valid) {
            sval = (d + bval) / (float)E;
            contrib += -log_sigmoid_f(sval - lgt) / (float)B + 10.0f * s2 / ((float)E * (float)B);
        }
        sh_s[threadIdx.x] = sval;
    }
    __syncthreads();
    if (valid) {
        const float sval = sh_s[p];
        float nacc = 0.0f;
        if (has0) nacc = log_sigmoid_f(-(sval - lg0));
        for (int k = g + 16; k < NC; k += 16) {
            const int n = noises[j + (size_t)k * B];
            nacc += log_sigmoid_f(-(sval - logf((float)NC * freq[n])));
        }
        contrib += -nacc / (float)B;
    }
    #pragma unroll
    for (int off = 32; off > 0; off >>= 1) contrib += __shfl_xor(contrib, off, 64);
    if ((threadIdx.x & 63) == 0) sh_wred[threadIdx.x >> 6] = contrib;
    __syncthreads();
    if (threadIdx.x == 0)
        block_partials[blockIdx.x] = sh_wred[0] + sh_wred[1] + sh_wred[2] + sh_wred[3];
}

extern "C" void kernel_launch(void* const* d_in, const int* in_sizes, int n_in,
                              void* d_out, int out_size, void* d_ws, size_t ws_size,
                              hipStream_t stream) {
    const float* embed    = (const float*)d_in[0];
    const float* bias     = (const float*)d_in[1];
    const float* freq     = (const float*)d_in[2];
    const int*   targets  = (const int*)d_in[3];
    const int*   contexts = (const int*)d_in[4];
    const int*   noises   = (const int*)d_in[5];

    const int V  = in_sizes[2];
    const int E  = in_sizes[0] / V;
    const int B  = in_sizes[3];
    const int NC = in_sizes[5] / B;
    const int T2 = 2 * B;

    // ws layout
    char* ws = (char*)d_ws;
    float* partials = (float*)ws;                       // 16 KB (4096 floats)
    int*   counts   = (int*)(ws + 16384);               // NB ints
    int*   cursors  = (int*)(ws + 16384 + NB * 4);      // NB ints
    int*   sorted   = (int*)(ws + 16384 + 2 * NB * 4);
    int*   invperm  = sorted + T2;
    size_t dense_off = 16384 + 2 * (size_t)NB * 4 + 2 * (size_t)T2 * 4;
    dense_off = (dense_off + 255) & ~(size_t)255;
    float* dense = (float*)(ws + dense_off);
    const size_t needed = dense_off + (size_t)T2 * 128 * 4;

    const int nblocks = (B + 15) / 16;

    if (E == 128 && (B & 15) == 0 && ws_size >= needed) {
        int sh = 0;
        while ((((V - 1) >> sh) + 1) > NB) ++sh;        // V=1e6 -> sh=9, nb=1954
        const int nb = ((V - 1) >> sh) + 1;

        hipMemsetAsync(counts, 0, (size_t)NB * 4, stream);
        hist_kernel<<<(T2 + 255) / 256, 256, 0, stream>>>(targets, contexts, counts, T2, sh);
        scan_kernel<<<1, 1024, 0, stream>>>(counts, cursors, nb);
        scatter_kernel<<<(T2 + 255) / 256, 256, 0, stream>>>(targets, contexts, cursors,
                                                             sorted, invperm, T2, sh);
        gather_kernel<<<(T2 + 15) / 16, 256, 0, stream>>>(embed, targets, contexts,
                                                          sorted, dense, V, T2);
        compute_kernel<<<nblocks, 256, 0, stream>>>(dense, invperm, bias, freq,
                                                    targets, noises, partials, B, NC);
    } else {
        nce_fallback<<<nblocks, 256, 0, stream>>>(embed, bias, freq, targets, contexts,
                                                  noises, partials, V, E, B, NC);
    }
    reduce_partials_kernel<<<1, 256, 0, stream>>>(partials, nblocks, (float*)d_out);
}

// Round 5
// 102.172 us; speedup vs baseline: 1.0053x; 1.0053x over previous
//
#include <hip/hip_runtime.h>
#include <hip/hip_bf16.h>
#include <math.h>

// NCE loss, sorted-gather pipeline (low-overhead version):
//   K1 hist -> K2 scan (1-block, 3-level) -> K3 scatter (counting sort of the
//   2B column-gather tasks by column bucket) -> K4 gather sorted columns into
//   bf16 dense[2B][128] (coalesced 256B-row stores) -> K5 per-pair compute ->
//   K6 reduce.
// Sorting makes same-cache-line columns temporally adjacent so L1/L2 dedup
// them; bf16 dense halves the scratch round-trip (precision ok: 2% threshold).

#define NB 2048

struct alignas(16) bf16x8 { __hip_bfloat16 h[8]; };

__device__ __forceinline__ float log_sigmoid_f(float x) {
    return fminf(x, 0.0f) - log1pf(expf(-fabsf(x)));
}

__device__ __forceinline__ int task_col(int i, const int* __restrict__ targets,
                                        const int* __restrict__ contexts) {
    const int pair = i >> 1;
    return (i & 1) ? contexts[pair] : targets[pair];
}

// ---- K1: histogram of task columns into buckets ----
__global__ __launch_bounds__(256) void hist_kernel(
    const int* __restrict__ targets, const int* __restrict__ contexts,
    int* __restrict__ counts, int T2, int sh)
{
    const int i = blockIdx.x * 256 + threadIdx.x;
    if (i < T2) atomicAdd(&counts[task_col(i, targets, contexts) >> sh], 1);
}

// ---- K2: exclusive scan of counts -> cursors (single block, 256 thr) ----
__global__ __launch_bounds__(256) void scan_kernel(
    const int* __restrict__ counts, int* __restrict__ cursors, int nb)
{
    __shared__ int wv_tot[4];
    const int tid  = threadIdx.x;
    const int lane = tid & 63;
    const int w    = tid >> 6;
    int v[8];
    const int base = tid * 8;
    int local = 0;
    #pragma unroll
    for (int k = 0; k < 8; ++k) {
        const int idx = base + k;
        v[k] = (idx < nb) ? counts[idx] : 0;
        local += v[k];
    }
    // wave-inclusive scan of per-thread totals
    int incl = local;
    #pragma unroll
    for (int off = 1; off < 64; off <<= 1) {
        const int n = __shfl_up(incl, off, 64);
        if (lane >= off) incl += n;
    }
    if (lane == 63) wv_tot[w] = incl;
    __syncthreads();
    int wpre = 0;
    for (int i = 0; i < w; ++i) wpre += wv_tot[i];
    int run = wpre + incl - local;          // exclusive prefix of this thread
    #pragma unroll
    for (int k = 0; k < 8; ++k) {
        const int idx = base + k;
        if (idx < nb) cursors[idx] = run;
        run += v[k];
    }
}

// ---- K3: scatter tasks to sorted positions ----
__global__ __launch_bounds__(256) void scatter_kernel(
    const int* __restrict__ targets, const int* __restrict__ contexts,
    int* __restrict__ cursors, int* __restrict__ sorted,
    int* __restrict__ invperm, int T2, int sh)
{
    const int i = blockIdx.x * 256 + threadIdx.x;
    if (i < T2) {
        const int col = task_col(i, targets, contexts);
        const int pos = atomicAdd(&cursors[col >> sh], 1);
        sorted[pos] = i;
        invperm[i]  = pos;
    }
}

// ---- K4: gather sorted columns into bf16 dense[pos][128] ----
// tid = g + 16*p : 16 consecutive lanes cover one task's full 256B row
// -> coalesced dwordx4 stores.
__global__ __launch_bounds__(256) void gather_kernel(
    const float* __restrict__ embed,
    const int* __restrict__ targets, const int* __restrict__ contexts,
    const int* __restrict__ sorted, bf16x8* __restrict__ dense,
    int V, int T2)
{
    const int g = threadIdx.x & 15;        // e-chunk 0..15 (8 elems)
    const int p = threadIdx.x >> 4;        // task slot 0..15
    const int pos = blockIdx.x * 16 + p;
    if (pos >= T2) return;
    const int col = task_col(sorted[pos], targets, contexts);
    const float* src = embed + col + (size_t)(g * 8) * V;
    float v[8];
    #pragma unroll
    for (int k = 0; k < 8; ++k) v[k] = src[(size_t)k * V];
    bf16x8 outv;
    #pragma unroll
    for (int k = 0; k < 8; ++k) outv.h[k] = __float2bfloat16(v[k]);
    dense[(size_t)pos * 16 + g] = outv;    // 16B store, row = 16 chunks
}

// ---- K5: per-pair compute from bf16 dense ----
__global__ __launch_bounds__(256) void compute_kernel(
    const bf16x8* __restrict__ dense, const int* __restrict__ invperm,
    const float* __restrict__ bias, const float* __restrict__ freq,
    const int* __restrict__ targets, const int* __restrict__ noises,
    float* __restrict__ partials, int B, int NC)
{
    __shared__ float sh_dot[16][17];
    __shared__ float sh_sq [16][17];
    __shared__ float sh_s  [16];
    __shared__ float sh_wred[4];

    const int p = threadIdx.x & 15;        // pair slot
    const int g = threadIdx.x >> 4;        // e-chunk
    const int j = blockIdx.x * 16 + p;
    const bool valid = (j < B);

    float contrib = 0.0f;
    float dot = 0.0f, sq = 0.0f;
    float lg0 = 0.0f; bool has0 = false;
    float bval = 0.0f, lgt = 0.0f;

    if (valid) {
        if (g < NC) {
            const int n = noises[j + (size_t)g * B];
            lg0 = logf((float)NC * freq[n]);
            has0 = true;
        }
        if (g == 0) {
            const int t = targets[j];
            bval = bias[t];
            lgt  = logf((float)NC * freq[t]);
        }
        const bf16x8 qv = dense[(size_t)invperm[2 * j]     * 16 + g];
        const bf16x8 rv = dense[(size_t)invperm[2 * j + 1] * 16 + g];
        #pragma unroll
        for (int k = 0; k < 8; ++k) {
            const float qe = __bfloat162float(qv.h[k]);
            const float re = __bfloat162float(rv.h[k]);
            dot = fmaf(qe, re, dot);
            sq  = fmaf(qe, qe, fmaf(re, re, sq));
        }
    }
    sh_dot[p][g] = dot;
    sh_sq [p][g] = sq;
    __syncthreads();

    if (threadIdx.x < 16) {
        float d = 0.0f, s2 = 0.0f;
        #pragma unroll
        for (int gg = 0; gg < 16; ++gg) {
            d  += sh_dot[threadIdx.x][gg];
            s2 += sh_sq [threadIdx.x][gg];
        }
        float sval = 0.0f;
        if (valid) {
            sval = (d + bval) / 128.0f;
            const float pos = log_sigmoid_f(sval - lgt);
            contrib += -pos / (float)B + 10.0f * s2 / (128.0f * (float)B);
        }
        sh_s[threadIdx.x] = sval;
    }
    __syncthreads();

    if (valid) {
        const float sval = sh_s[p];
        float nacc = 0.0f;
        if (has0) nacc = log_sigmoid_f(-(sval - lg0));
        for (int k = g + 16; k < NC; k += 16) {
            const int n = noises[j + (size_t)k * B];
            nacc += log_sigmoid_f(-(sval - logf((float)NC * freq[n])));
        }
        contrib += -nacc / (float)B;
    }

    #pragma unroll
    for (int off = 32; off > 0; off >>= 1)
        contrib += __shfl_xor(contrib, off, 64);
    if ((threadIdx.x & 63) == 0) sh_wred[threadIdx.x >> 6] = contrib;
    __syncthreads();
    if (threadIdx.x == 0)
        partials[blockIdx.x] = sh_wred[0] + sh_wred[1] + sh_wred[2] + sh_wred[3];
}

__global__ __launch_bounds__(256) void reduce_partials_kernel(
    const float* __restrict__ parts, int n, float* __restrict__ out)
{
    __shared__ double sh[256];
    double a = 0.0;
    for (int i = threadIdx.x; i < n; i += 256) a += (double)parts[i];
    sh[threadIdx.x] = a;
    __syncthreads();
    for (int s = 128; s > 0; s >>= 1) {
        if (threadIdx.x < s) sh[threadIdx.x] += sh[threadIdx.x + s];
        __syncthreads();
    }
    if (threadIdx.x == 0) out[0] = (float)sh[0];
}

// ---- fallback (R3 structure, fp32 direct gather) if ws too small ----
__global__ __launch_bounds__(256) void nce_fallback(
    const float* __restrict__ embed, const float* __restrict__ bias,
    const float* __restrict__ freq, const int* __restrict__ targets,
    const int* __restrict__ contexts, const int* __restrict__ noises,
    float* __restrict__ block_partials, int V, int E, int B, int NC)
{
    __shared__ float sh_dot[16][17];
    __shared__ float sh_sq [16][17];
    __shared__ float sh_s  [16];
    __shared__ float sh_wred[4];
    const int p = threadIdx.x & 15;
    const int g = threadIdx.x >> 4;
    const int j = blockIdx.x * 16 + p;
    const bool valid = (j < B);
    float contrib = 0.0f, dot = 0.0f, sq = 0.0f;
    float lg0 = 0.0f; bool has0 = false; float bval = 0.0f, lgt = 0.0f;
    if (valid) {
        const int t = targets[j], c = contexts[j];
        if (g < NC) { const int n = noises[j + (size_t)g * B];
                      lg0 = logf((float)NC * freq[n]); has0 = true; }
        if (g == 0) { bval = bias[t]; lgt = logf((float)NC * freq[t]); }
        const int epc = E / 16, e0 = g * epc;
        const float* ct = embed + t; const float* cc = embed + c;
        #pragma unroll 8
        for (int e = e0; e < e0 + epc; ++e) {
            float qe = ct[(size_t)e * V], re = cc[(size_t)e * V];
            dot = fmaf(qe, re, dot);
            sq  = fmaf(qe, qe, fmaf(re, re, sq));
        }
    }
    sh_dot[p][g] = dot; sh_sq[p][g] = sq;
    __syncthreads();
    if (threadIdx.x < 16) {
        float d = 0.0f, s2 = 0.0f;
        #pragma unroll
        for (int gg = 0; gg < 16; ++gg) { d += sh_dot[threadIdx.x][gg]; s2 += sh_sq[threadIdx.x][gg]; }
        float sval = 0.0f;
        if (valid) {
            sval = (d + bval) / (float)E;
            contrib += -log_sigmoid_f(sval - lgt) / (float)B + 10.0f * s2 / ((float)E * (float)B);
        }
        sh_s[threadIdx.x] = sval;
    }
    __syncthreads();
    if (valid) {
        const float sval = sh_s[p];
        float nacc = 0.0f;
        if (has0) nacc = log_sigmoid_f(-(sval - lg0));
        for (int k = g + 16; k < NC; k += 16) {
            const int n = noises[j + (size_t)k * B];
            nacc += log_sigmoid_f(-(sval - logf((float)NC * freq[n])));
        }
        contrib += -nacc / (float)B;
    }
    #pragma unroll
    for (int off = 32; off > 0; off >>= 1) contrib += __shfl_xor(contrib, off, 64);
    if ((threadIdx.x & 63) == 0) sh_wred[threadIdx.x >> 6] = contrib;
    __syncthreads();
    if (threadIdx.x == 0)
        block_partials[blockIdx.x] = sh_wred[0] + sh_wred[1] + sh_wred[2] + sh_wred[3];
}

extern "C" void kernel_launch(void* const* d_in, const int* in_sizes, int n_in,
                              void* d_out, int out_size, void* d_ws, size_t ws_size,
                              hipStream_t stream) {
    const float* embed    = (const float*)d_in[0];
    const float* bias     = (const float*)d_in[1];
    const float* freq     = (const float*)d_in[2];
    const int*   targets  = (const int*)d_in[3];
    const int*   contexts = (const int*)d_in[4];
    const int*   noises   = (const int*)d_in[5];

    const int V  = in_sizes[2];
    const int E  = in_sizes[0] / V;
    const int B  = in_sizes[3];
    const int NC = in_sizes[5] / B;
    const int T2 = 2 * B;

    // ws layout
    char* ws = (char*)d_ws;
    float* partials = (float*)ws;                        // 16 KB
    int*   counts   = (int*)(ws + 16384);                // NB ints (8 KB)
    int*   cursors  = counts + NB;                       // NB ints (8 KB)
    int*   sorted   = cursors + NB;                      // T2 ints
    int*   invperm  = sorted + T2;                       // T2 ints
    size_t dense_off = 16384 + 2 * (size_t)NB * 4 + 2 * (size_t)T2 * 4;
    dense_off = (dense_off + 255) & ~(size_t)255;
    bf16x8* dense = (bf16x8*)(ws + dense_off);
    const size_t needed = dense_off + (size_t)T2 * 128 * 2;  // bf16 dense

    const int nblocks = (B + 15) / 16;

    if (E == 128 && (B & 15) == 0 && ws_size >= needed) {
        int sh = 0;
        while ((((V - 1) >> sh) + 1) > NB) ++sh;         // V=1e6 -> sh=9
        const int nb = ((V - 1) >> sh) + 1;

        hipMemsetAsync(counts, 0, (size_t)NB * 4, stream);
        hist_kernel<<<(T2 + 255) / 256, 256, 0, stream>>>(targets, contexts, counts, T2, sh);
        scan_kernel<<<1, 256, 0, stream>>>(counts, cursors, nb);
        scatter_kernel<<<(T2 + 255) / 256, 256, 0, stream>>>(targets, contexts, cursors,
                                                             sorted, invperm, T2, sh);
        gather_kernel<<<(T2 + 15) / 16, 256, 0, stream>>>(embed, targets, contexts,
                                                          sorted, dense, V, T2);
        compute_kernel<<<nblocks, 256, 0, stream>>>(dense, invperm, bias, freq,
                                                    targets, noises, partials, B, NC);
    } else {
        nce_fallback<<<nblocks, 256, 0, stream>>>(embed, bias, freq, targets, contexts,
                                                  noises, partials, V, E, B, NC);
    }
    reduce_partials_kernel<<<1, 256, 0, stream>>>(partials, nblocks, (float*)d_out);
}